// Round 1
// baseline (187.539 us; speedup 1.0000x reference)
//
#include <hip/hip_runtime.h>

// Problem constants (from reference): x (N,D,L) f32, weight (K,D) f32, scale (1,) f32
// out (N,K,L) f32 = (||x||^2 + ||c||^2 - 2 x.c) / scale^2
#define N_ 32
#define D_ 128
#define L_ 3136
#define K_ 64

// One thread per (n,l) column; all K=64 accumulators in VGPRs.
// Weight reads are wave-uniform -> scalar loads (SGPR operand to v_fmac).
// block=64 (1 wave), grid=(L/64, N)=(49,32): L=49*64 exactly, no tail.
__global__ __launch_bounds__(64) void enc_dist_kernel(
    const float* __restrict__ x,
    const float* __restrict__ w,
    const float* __restrict__ scale,
    float* __restrict__ out)
{
    const int tid = threadIdx.x;      // 0..63
    const int n   = blockIdx.y;       // 0..31
    const int l   = blockIdx.x * 64 + tid;

    // ---- per-block ||c_k||^2 into LDS (thread k handles row k) ----
    __shared__ float c_sq[K_];
    {
        const float* wr = w + (size_t)tid * D_;
        float s = 0.f;
#pragma unroll
        for (int d = 0; d < D_; d += 4) {
            float4 wv = *(const float4*)(wr + d);
            s = fmaf(wv.x, wv.x, s);
            s = fmaf(wv.y, wv.y, s);
            s = fmaf(wv.z, wv.z, s);
            s = fmaf(wv.w, wv.w, s);
        }
        c_sq[tid] = s;
    }
    __syncthreads();

    // ---- main loop: acc[k] = sum_d x[n,d,l] * w[k,d]; x_sq = sum_d x^2 ----
    const float* xp = x + (size_t)n * D_ * L_ + l;

    float acc[K_];
#pragma unroll
    for (int k = 0; k < K_; ++k) acc[k] = 0.f;
    float x_sq = 0.f;

    for (int d0 = 0; d0 < D_; d0 += 8) {
        float xv[8];
#pragma unroll
        for (int i = 0; i < 8; ++i) xv[i] = xp[(size_t)(d0 + i) * L_];
#pragma unroll
        for (int i = 0; i < 8; ++i) x_sq = fmaf(xv[i], xv[i], x_sq);
#pragma unroll
        for (int k = 0; k < K_; ++k) {
            float a = acc[k];
            const float* wr = w + (size_t)k * D_ + d0;  // uniform -> s_load
#pragma unroll
            for (int i = 0; i < 8; ++i) a = fmaf(xv[i], wr[i], a);
            acc[k] = a;
        }
    }

    // ---- epilogue: fuse the three terms, scale, coalesced stores ----
    const float sc = scale[0];
    const float inv_s2 = 1.0f / (sc * sc);
    float* op = out + (size_t)n * K_ * L_ + l;
#pragma unroll
    for (int k = 0; k < K_; ++k) {
        op[(size_t)k * L_] = (x_sq + c_sq[k] - 2.0f * acc[k]) * inv_s2;
    }
}

extern "C" void kernel_launch(void* const* d_in, const int* in_sizes, int n_in,
                              void* d_out, int out_size, void* d_ws, size_t ws_size,
                              hipStream_t stream) {
    const float* x     = (const float*)d_in[0];
    const float* w     = (const float*)d_in[1];
    const float* scale = (const float*)d_in[2];
    float* out = (float*)d_out;

    dim3 grid(L_ / 64, N_);   // (49, 32) = 1568 blocks, no tail
    enc_dist_kernel<<<grid, 64, 0, stream>>>(x, w, scale, out);
}